// Round 5
// baseline (303.706 us; speedup 1.0000x reference)
//
#include <hip/hip_runtime.h>
#include <math.h>

#define D 100
#define NEG_SLOPE 0.2f
#define CHUNK 32
#define ROWU 50          // uints per staged bf16 row (100 dims * 2B / 4B)

// pack two fp32 -> (bf16,bf16) in one uint, round-to-nearest-even
__device__ __forceinline__ unsigned int pack_bf16x2(float x, float y) {
    unsigned int ux = __float_as_uint(x), uy = __float_as_uint(y);
    ux += 0x7FFFu + ((ux >> 16) & 1u);
    uy += 0x7FFFu + ((uy >> 16) & 1u);
    return (ux >> 16) | (uy & 0xFFFF0000u);
}

__device__ __forceinline__ float dot4(float4 a, float4 b) {
    return a.x * b.x + a.y * b.y + a.z * b.z + a.w * b.w;
}

// Pair-parallel boundary scatter: row_ptr[v] = first pair index with seg >= v.
__global__ void build_row_ptr(const int* __restrict__ seg,
                              int* __restrict__ row_ptr,
                              int n, int P)
{
    int p = blockIdx.x * blockDim.x + threadIdx.x;
    if (p >= P) return;
    int s0 = seg[p];
    if (p == 0)
        for (int v = 0; v <= s0; v++) row_ptr[v] = 0;
    int s1 = (p + 1 < P) ? seg[p + 1] : n;
    for (int v = s0 + 1; v <= s1; v++) row_ptr[v] = p + 1;
}

// One wave per node. Phase A: 2 lanes/pair; prefetch the whole half-row into
// registers (13 loads in flight), 4-accumulator dot, stage bf16 row to LDS.
// Phase B: lane-per-dim accumulate; e read from LDS as float4 broadcast
// (1 DS op per 4 pairs) + paired row reads (ds_read2-friendly).
__launch_bounds__(256, 5)   // cap VGPR at 102; occupancy limiter is LDS (5 blk/CU)
__global__ void gat_agg_kernel(const float* __restrict__ hidden,
                               const float* __restrict__ W,
                               const int* __restrict__ nbr,
                               const int* __restrict__ row_ptr,
                               float* __restrict__ out,
                               int n)
{
    __shared__ __align__(16) float        s_hw[4][104];           // 1.66 KB
    __shared__ __align__(16) unsigned int s_rows[4][CHUNK][ROWU]; // 25.6 KB
    __shared__ __align__(16) float        s_e[4][CHUNK];          // 0.5 KB

    const int lane = threadIdx.x & 63;
    const int wid  = threadIdx.x >> 6;
    const int v    = blockIdx.x * 4 + wid;
    if (v >= n) return;          // wave-uniform exit; no block barriers used

    // hw[d] = hidden[v][d] * W[d], staged once in LDS (broadcast source)
    s_hw[wid][lane] = hidden[(long)v * D + lane] * W[lane];
    if (lane < D - 64)
        s_hw[wid][64 + lane] = hidden[(long)v * D + 64 + lane] * W[64 + lane];
    __threadfence_block();

    const float4* hw4 = (const float4*)&s_hw[wid][0];

    const int start = row_ptr[v];
    const int end   = row_ptr[v + 1];

    if (end <= start) {          // empty segment: zeros (matches reference)
        if (lane < D / 2)
            ((float2*)(out + (long)v * D))[lane] = make_float2(0.f, 0.f);
        return;
    }

    const int half = lane >> 5;          // 0: float4s 0..12, 1: 13..24
    const int jl   = lane & 31;          // pair slot within the 32-chunk

    float m = -INFINITY, z = 0.f;
    float accx = 0.f, accy = 0.f;

    for (int c = start; c < end; c += CHUNK) {
        const int  cnt = min(CHUNK, end - c);
        const bool pv  = jl < cnt;

        // ---- Phase A: prefetch half-row -> 4-acc dot -> bf16 stage ----
        // invalid lanes read row 0 (finite, in-bounds); e=0 masks it later
        const int nbv = pv ? nbr[c + jl] : 0;
        const float4* row4 = (const float4*)(hidden + (long)nbv * D) + half * 13;
        const float4* hwh  = hw4 + half * 13;
        uint2* dst = (uint2*)&s_rows[wid][jl][half * 26];

        float4 b[12];
        #pragma unroll
        for (int k = 0; k < 12; k++) b[k] = row4[k];   // all loads in flight
        float4 b12;
        if (half == 0) b12 = row4[12];                 // odd float4: half 0 only

        float p0 = 0.f, p1 = 0.f, p2 = 0.f, p3 = 0.f;
        #pragma unroll
        for (int k = 0; k < 12; k += 4) {
            p0 += dot4(hwh[k    ], b[k    ]);
            p1 += dot4(hwh[k + 1], b[k + 1]);
            p2 += dot4(hwh[k + 2], b[k + 2]);
            p3 += dot4(hwh[k + 3], b[k + 3]);
        }
        if (half == 0) p0 += dot4(hw4[12], b12);
        float part = (p0 + p1) + (p2 + p3);

        #pragma unroll
        for (int k = 0; k < 12; k++)
            dst[k] = make_uint2(pack_bf16x2(b[k].x, b[k].y),
                                pack_bf16x2(b[k].z, b[k].w));
        if (half == 0)
            dst[12] = make_uint2(pack_bf16x2(b12.x, b12.y),
                                 pack_bf16x2(b12.z, b12.w));

        part += __shfl_xor(part, 32, 64);              // combine halves
        const float s = pv ? (part >= 0.f ? part : NEG_SLOPE * part)
                           : -INFINITY;

        // ---- online softmax: s duplicated across halves -> 5-step reductions
        float mx = s;
        #pragma unroll
        for (int off = 16; off >= 1; off >>= 1)
            mx = fmaxf(mx, __shfl_xor(mx, off, 64));
        const float m_new = fmaxf(m, mx);
        const float scale = __expf(m - m_new);         // first chunk: 0
        const float e     = pv ? __expf(s - m_new) : 0.f;
        float es = e;
        #pragma unroll
        for (int off = 16; off >= 1; off >>= 1)
            es += __shfl_xor(es, off, 64);             // sum over 32-group
        z = z * scale + es;
        accx *= scale; accy *= scale;

        if (half == 0) s_e[wid][jl] = e;               // stage e for phase B
        __threadfence_block();                         // LDS stores -> reads

        // ---- Phase B: lane-per-dim accumulate from bf16 LDS ----
        const int cnt4 = (cnt + 3) & ~3;
        if (lane < D / 2) {
            for (int j0 = 0; j0 < cnt4; j0 += 4) {
                const float4 ev = *(const float4*)&s_e[wid][j0];  // broadcast
                #pragma unroll
                for (int t = 0; t < 4; t += 2) {       // paired -> ds_read2
                    const unsigned int u0 = s_rows[wid][j0 + t    ][lane];
                    const unsigned int u1 = s_rows[wid][j0 + t + 1][lane];
                    const float e0 = (t == 0) ? ev.x : ev.z;
                    const float e1 = (t == 0) ? ev.y : ev.w;
                    accx += e0 * __uint_as_float(u0 << 16);
                    accy += e0 * __uint_as_float(u0 & 0xFFFF0000u);
                    accx += e1 * __uint_as_float(u1 << 16);
                    accy += e1 * __uint_as_float(u1 & 0xFFFF0000u);
                }
            }
        }
        __threadfence_block();   // phase-B reads done before next chunk's stores
        m = m_new;
    }

    if (lane < D / 2) {
        const float inv = 1.f / z;
        ((float2*)(out + (long)v * D))[lane] = make_float2(accx * inv, accy * inv);
    }
}

extern "C" void kernel_launch(void* const* d_in, const int* in_sizes, int n_in,
                              void* d_out, int out_size, void* d_ws, size_t ws_size,
                              hipStream_t stream) {
    const float* hidden = (const float*)d_in[0];
    const float* W      = (const float*)d_in[1];
    const int*   seg    = (const int*)d_in[2];
    const int*   nbr    = (const int*)d_in[3];
    float*       out    = (float*)d_out;

    const int Ddim = in_sizes[1];           // 100
    const int n    = in_sizes[0] / Ddim;    // 50000
    const int P    = in_sizes[2];           // ~1.3M pairs

    int* row_ptr = (int*)d_ws;              // (n+1) ints

    hipLaunchKernelGGL(build_row_ptr, dim3((P + 255) / 256), dim3(256), 0, stream,
                       seg, row_ptr, n, P);
    hipLaunchKernelGGL(gat_agg_kernel, dim3((n + 3) / 4), dim3(256), 0, stream,
                       hidden, W, nbr, row_ptr, out, n);
}

// Round 6
// 221.329 us; speedup vs baseline: 1.3722x; 1.3722x over previous
//
#include <hip/hip_runtime.h>
#include <math.h>

#define D 100
#define NEG_SLOPE 0.2f
#define CHUNK 32
#define ROWU 50          // uints per staged bf16 row (100 dims * 2B / 4B)

// pack two fp32 -> (bf16,bf16) in one uint, round-to-nearest-even
__device__ __forceinline__ unsigned int pack_bf16x2(float x, float y) {
    unsigned int ux = __float_as_uint(x), uy = __float_as_uint(y);
    ux += 0x7FFFu + ((ux >> 16) & 1u);
    uy += 0x7FFFu + ((uy >> 16) & 1u);
    return (ux >> 16) | (uy & 0xFFFF0000u);
}

__device__ __forceinline__ uint2 pk(float4 b) {
    return make_uint2(pack_bf16x2(b.x, b.y), pack_bf16x2(b.z, b.w));
}

__device__ __forceinline__ float dot4(float4 a, float4 b) {
    return a.x * b.x + a.y * b.y + a.z * b.z + a.w * b.w;
}

// Pair-parallel boundary scatter: row_ptr[v] = first pair index with seg >= v.
__global__ void build_row_ptr(const int* __restrict__ seg,
                              int* __restrict__ row_ptr,
                              int n, int P)
{
    int p = blockIdx.x * blockDim.x + threadIdx.x;
    if (p >= P) return;
    int s0 = seg[p];
    if (p == 0)
        for (int v = 0; v <= s0; v++) row_ptr[v] = 0;
    int s1 = (p + 1 < P) ? seg[p + 1] : n;
    for (int v = s0 + 1; v <= s1; v++) row_ptr[v] = p + 1;
}

// One wave per node. Phase A: 2 lanes/pair, 6-deep NAMED-register load pipeline
// (no indexed array -> no scratch spill), fp32 dot + bf16 LDS staging.
// Phase B: lane-per-dim accumulate; e from LDS float4 broadcast.
__launch_bounds__(256, 5)   // LDS (27.9K/block) limits to 5 blk/CU; VGPR cap 102
__global__ void gat_agg_kernel(const float* __restrict__ hidden,
                               const float* __restrict__ W,
                               const int* __restrict__ nbr,
                               const int* __restrict__ row_ptr,
                               float* __restrict__ out,
                               int n)
{
    __shared__ __align__(16) float        s_hw[4][104];           // 1.66 KB
    __shared__ __align__(16) unsigned int s_rows[4][CHUNK][ROWU]; // 25.6 KB
    __shared__ __align__(16) float        s_e[4][CHUNK];          // 0.5 KB

    const int lane = threadIdx.x & 63;
    const int wid  = threadIdx.x >> 6;
    const int v    = blockIdx.x * 4 + wid;
    if (v >= n) return;          // wave-uniform exit; no block barriers used

    // hw[d] = hidden[v][d] * W[d], staged once in LDS (broadcast source)
    s_hw[wid][lane] = hidden[(long)v * D + lane] * W[lane];
    if (lane < D - 64)
        s_hw[wid][64 + lane] = hidden[(long)v * D + 64 + lane] * W[64 + lane];
    __threadfence_block();

    const float4* hw4 = (const float4*)&s_hw[wid][0];

    const int start = row_ptr[v];
    const int end   = row_ptr[v + 1];

    if (end <= start) {          // empty segment: zeros (matches reference)
        if (lane < D / 2)
            ((float2*)(out + (long)v * D))[lane] = make_float2(0.f, 0.f);
        return;
    }

    const int half = lane >> 5;          // 0: float4s 0..12, 1: 13..24
    const int jl   = lane & 31;          // pair slot within the 32-chunk

    float m = -INFINITY, z = 0.f;
    float accx = 0.f, accy = 0.f;

    for (int c = start; c < end; c += CHUNK) {
        const int  cnt = min(CHUNK, end - c);
        const bool pv  = jl < cnt;

        // invalid lanes gather row 0 (finite, in-bounds); e=0 masks it later
        const int nbv = pv ? nbr[c + jl] : 0;
        const float4* row4 = (const float4*)(hidden + (long)nbv * D) + half * 13;
        const float4* hwh  = hw4 + half * 13;
        uint2* dst = (uint2*)&s_rows[wid][jl][half * 26];

        // ---- Phase A: 6-deep named-register pipeline (7 for half 0) ----
        float4 x0 = row4[0], x1 = row4[1], x2 = row4[2];
        float4 x3 = row4[3], x4 = row4[4], x5 = row4[5];
        float4 x6;
        if (half == 0) x6 = row4[12];    // odd float4, issued early

        float p0 = 0.f, p1 = 0.f, p2 = 0.f, p3 = 0.f;
        p0 += dot4(hwh[0],  x0); dst[0]  = pk(x0); x0 = row4[6];
        p1 += dot4(hwh[1],  x1); dst[1]  = pk(x1); x1 = row4[7];
        p2 += dot4(hwh[2],  x2); dst[2]  = pk(x2); x2 = row4[8];
        p3 += dot4(hwh[3],  x3); dst[3]  = pk(x3); x3 = row4[9];
        p0 += dot4(hwh[4],  x4); dst[4]  = pk(x4); x4 = row4[10];
        p1 += dot4(hwh[5],  x5); dst[5]  = pk(x5); x5 = row4[11];
        p2 += dot4(hwh[6],  x0); dst[6]  = pk(x0);
        p3 += dot4(hwh[7],  x1); dst[7]  = pk(x1);
        p0 += dot4(hwh[8],  x2); dst[8]  = pk(x2);
        p1 += dot4(hwh[9],  x3); dst[9]  = pk(x3);
        p2 += dot4(hwh[10], x4); dst[10] = pk(x4);
        p3 += dot4(hwh[11], x5); dst[11] = pk(x5);
        if (half == 0) { p0 += dot4(hw4[12], x6); dst[12] = pk(x6); }

        float part = (p0 + p1) + (p2 + p3);
        part += __shfl_xor(part, 32, 64);              // combine halves
        const float s = pv ? (part >= 0.f ? part : NEG_SLOPE * part)
                           : -INFINITY;

        // ---- online softmax: s duplicated across halves -> 5-step reductions
        float mx = s;
        #pragma unroll
        for (int off = 16; off >= 1; off >>= 1)
            mx = fmaxf(mx, __shfl_xor(mx, off, 64));
        const float m_new = fmaxf(m, mx);
        const float scale = __expf(m - m_new);         // first chunk: 0
        const float e     = pv ? __expf(s - m_new) : 0.f;
        float es = e;
        #pragma unroll
        for (int off = 16; off >= 1; off >>= 1)
            es += __shfl_xor(es, off, 64);             // sum within 32-group
        z = z * scale + es;
        accx *= scale; accy *= scale;

        if (half == 0) s_e[wid][jl] = e;               // e=0 on tail slots
        __threadfence_block();                         // LDS stores -> reads

        // ---- Phase B: lane-per-dim accumulate from bf16 LDS ----
        const int cnt4 = (cnt + 3) & ~3;
        if (lane < D / 2) {
            for (int j0 = 0; j0 < cnt4; j0 += 4) {
                const float4 ev = *(const float4*)&s_e[wid][j0];  // broadcast
                const unsigned int u0 = s_rows[wid][j0    ][lane];
                const unsigned int u1 = s_rows[wid][j0 + 1][lane];
                const unsigned int u2 = s_rows[wid][j0 + 2][lane];
                const unsigned int u3 = s_rows[wid][j0 + 3][lane];
                accx += ev.x * __uint_as_float(u0 << 16);
                accy += ev.x * __uint_as_float(u0 & 0xFFFF0000u);
                accx += ev.y * __uint_as_float(u1 << 16);
                accy += ev.y * __uint_as_float(u1 & 0xFFFF0000u);
                accx += ev.z * __uint_as_float(u2 << 16);
                accy += ev.z * __uint_as_float(u2 & 0xFFFF0000u);
                accx += ev.w * __uint_as_float(u3 << 16);
                accy += ev.w * __uint_as_float(u3 & 0xFFFF0000u);
            }
        }
        __threadfence_block();   // phase-B reads done before next chunk's stores
        m = m_new;
    }

    if (lane < D / 2) {
        const float inv = 1.f / z;
        ((float2*)(out + (long)v * D))[lane] = make_float2(accx * inv, accy * inv);
    }
}

extern "C" void kernel_launch(void* const* d_in, const int* in_sizes, int n_in,
                              void* d_out, int out_size, void* d_ws, size_t ws_size,
                              hipStream_t stream) {
    const float* hidden = (const float*)d_in[0];
    const float* W      = (const float*)d_in[1];
    const int*   seg    = (const int*)d_in[2];
    const int*   nbr    = (const int*)d_in[3];
    float*       out    = (float*)d_out;

    const int Ddim = in_sizes[1];           // 100
    const int n    = in_sizes[0] / Ddim;    // 50000
    const int P    = in_sizes[2];           // ~1.3M pairs

    int* row_ptr = (int*)d_ws;              // (n+1) ints

    hipLaunchKernelGGL(build_row_ptr, dim3((P + 255) / 256), dim3(256), 0, stream,
                       seg, row_ptr, n, P);
    hipLaunchKernelGGL(gat_agg_kernel, dim3((n + 3) / 4), dim3(256), 0, stream,
                       hidden, W, nbr, row_ptr, out, n);
}

// Round 7
// 170.814 us; speedup vs baseline: 1.7780x; 1.2957x over previous
//
#include <hip/hip_runtime.h>
#include <math.h>

#define D 100
#define NEG_SLOPE 0.2f
#define CHUNK 32
#define ROWU 50          // uints per staged bf16 row (100 dims * 2B / 4B)

// pack two fp32 -> (bf16,bf16) in one uint, round-to-nearest-even
__device__ __forceinline__ unsigned int pack_bf16x2(float x, float y) {
    unsigned int ux = __float_as_uint(x), uy = __float_as_uint(y);
    ux += 0x7FFFu + ((ux >> 16) & 1u);
    uy += 0x7FFFu + ((uy >> 16) & 1u);
    return (ux >> 16) | (uy & 0xFFFF0000u);
}

__device__ __forceinline__ uint2 pk(float4 b) {
    return make_uint2(pack_bf16x2(b.x, b.y), pack_bf16x2(b.z, b.w));
}

__device__ __forceinline__ float dot4(float4 a, float4 b) {
    return a.x * b.x + a.y * b.y + a.z * b.z + a.w * b.w;
}

// Pair-parallel boundary scatter: row_ptr[v] = first pair index with seg >= v.
__global__ void build_row_ptr(const int* __restrict__ seg,
                              int* __restrict__ row_ptr,
                              int n, int P)
{
    int p = blockIdx.x * blockDim.x + threadIdx.x;
    if (p >= P) return;
    int s0 = seg[p];
    if (p == 0)
        for (int v = 0; v <= s0; v++) row_ptr[v] = 0;
    int s1 = (p + 1 < P) ? seg[p + 1] : n;
    for (int v = s0 + 1; v <= s1; v++) row_ptr[v] = p + 1;
}

// One wave per node. Phase A: 2 lanes/pair; grouped load/consume pipeline with
// sched_barrier(0) fences to cap register pressure (the scheduler otherwise
// hoists all 13 gathers + 13 LDS reads -> >96 live regs -> scratch spill, the
// R5/R6 regression). Phase B: lane-per-dim accumulate from bf16 LDS.
__launch_bounds__(256, 5)   // LDS (27.9K/block) limits to 5 blk/CU; VGPR cap ~96
__global__ void gat_agg_kernel(const float* __restrict__ hidden,
                               const float* __restrict__ W,
                               const int* __restrict__ nbr,
                               const int* __restrict__ row_ptr,
                               float* __restrict__ out,
                               int n)
{
    __shared__ __align__(16) float        s_hw[4][104];           // 1.66 KB
    __shared__ __align__(16) unsigned int s_rows[4][CHUNK][ROWU]; // 25.6 KB
    __shared__ __align__(16) float        s_e[4][CHUNK];          // 0.5 KB

    const int lane = threadIdx.x & 63;
    const int wid  = threadIdx.x >> 6;
    const int v    = blockIdx.x * 4 + wid;
    if (v >= n) return;          // wave-uniform exit; no block barriers used

    // hw[d] = hidden[v][d] * W[d], staged once in LDS (broadcast source)
    s_hw[wid][lane] = hidden[(long)v * D + lane] * W[lane];
    if (lane < D - 64)
        s_hw[wid][64 + lane] = hidden[(long)v * D + 64 + lane] * W[64 + lane];
    __threadfence_block();

    const float4* hw4 = (const float4*)&s_hw[wid][0];

    const int start = row_ptr[v];
    const int end   = row_ptr[v + 1];

    if (end <= start) {          // empty segment: zeros (matches reference)
        if (lane < D / 2)
            ((float2*)(out + (long)v * D))[lane] = make_float2(0.f, 0.f);
        return;
    }

    const int half = lane >> 5;          // 0: float4s 0..12, 1: 13..24
    const int jl   = lane & 31;          // pair slot within the 32-chunk

    float m = -INFINITY, z = 0.f;
    float accx = 0.f, accy = 0.f;

    for (int c = start; c < end; c += CHUNK) {
        const int  cnt = min(CHUNK, end - c);
        const bool pv  = jl < cnt;

        // invalid lanes gather row 0 (finite, in-bounds); e=0 masks it later
        const int nbv = pv ? nbr[c + jl] : 0;
        const float4* row4 = (const float4*)(hidden + (long)nbv * D) + half * 13;
        const float4* hwh  = hw4 + half * 13;
        uint2* dst = (uint2*)&s_rows[wid][jl][half * 26];

        float p0 = 0.f, p1 = 0.f, p2 = 0.f, p3 = 0.f;

        // ---- region 1: issue G0+G1 (8-9 loads in flight), consume G0 ----
        float4 x0 = row4[0], x1 = row4[1], x2 = row4[2], x3 = row4[3];
        float4 xE;
        if (half == 0) xE = row4[12];    // odd float4, half 0 only
        float4 x4 = row4[4], x5 = row4[5], x6 = row4[6], x7 = row4[7];

        p0 += dot4(hwh[0], x0); dst[0] = pk(x0);
        p1 += dot4(hwh[1], x1); dst[1] = pk(x1);
        p2 += dot4(hwh[2], x2); dst[2] = pk(x2);
        p3 += dot4(hwh[3], x3); dst[3] = pk(x3);
        if (half == 0) { p0 += dot4(hw4[12], xE); dst[12] = pk(xE); }
        __builtin_amdgcn_sched_barrier(0);   // fence: cap live-range hoisting

        // ---- region 2: issue G2, consume G1 ----
        x0 = row4[8]; x1 = row4[9]; x2 = row4[10]; x3 = row4[11];
        p0 += dot4(hwh[4], x4); dst[4] = pk(x4);
        p1 += dot4(hwh[5], x5); dst[5] = pk(x5);
        p2 += dot4(hwh[6], x6); dst[6] = pk(x6);
        p3 += dot4(hwh[7], x7); dst[7] = pk(x7);
        __builtin_amdgcn_sched_barrier(0);

        // ---- region 3: consume G2 ----
        p0 += dot4(hwh[8],  x0); dst[8]  = pk(x0);
        p1 += dot4(hwh[9],  x1); dst[9]  = pk(x1);
        p2 += dot4(hwh[10], x2); dst[10] = pk(x2);
        p3 += dot4(hwh[11], x3); dst[11] = pk(x3);

        float part = (p0 + p1) + (p2 + p3);
        part += __shfl_xor(part, 32, 64);              // combine halves
        const float s = pv ? (part >= 0.f ? part : NEG_SLOPE * part)
                           : -INFINITY;

        // ---- online softmax: s duplicated across halves -> 5-step reductions
        float mx = s;
        #pragma unroll
        for (int off = 16; off >= 1; off >>= 1)
            mx = fmaxf(mx, __shfl_xor(mx, off, 64));
        const float m_new = fmaxf(m, mx);
        const float scale = __expf(m - m_new);         // first chunk: 0
        const float e     = pv ? __expf(s - m_new) : 0.f;
        float es = e;
        #pragma unroll
        for (int off = 16; off >= 1; off >>= 1)
            es += __shfl_xor(es, off, 64);             // sum within 32-group
        z = z * scale + es;
        accx *= scale; accy *= scale;

        if (half == 0) s_e[wid][jl] = e;               // e=0 on tail slots
        __threadfence_block();                         // LDS stores -> reads

        // ---- Phase B: lane-per-dim accumulate from bf16 LDS ----
        const int cnt4 = (cnt + 3) & ~3;
        if (lane < D / 2) {
            for (int j0 = 0; j0 < cnt4; j0 += 4) {
                const float4 ev = *(const float4*)&s_e[wid][j0];  // broadcast
                const unsigned int u0 = s_rows[wid][j0    ][lane];
                const unsigned int u1 = s_rows[wid][j0 + 1][lane];
                const unsigned int u2 = s_rows[wid][j0 + 2][lane];
                const unsigned int u3 = s_rows[wid][j0 + 3][lane];
                accx += ev.x * __uint_as_float(u0 << 16);
                accy += ev.x * __uint_as_float(u0 & 0xFFFF0000u);
                accx += ev.y * __uint_as_float(u1 << 16);
                accy += ev.y * __uint_as_float(u1 & 0xFFFF0000u);
                accx += ev.z * __uint_as_float(u2 << 16);
                accy += ev.z * __uint_as_float(u2 & 0xFFFF0000u);
                accx += ev.w * __uint_as_float(u3 << 16);
                accy += ev.w * __uint_as_float(u3 & 0xFFFF0000u);
            }
        }
        __threadfence_block();   // phase-B reads done before next chunk's stores
        m = m_new;
    }

    if (lane < D / 2) {
        const float inv = 1.f / z;
        ((float2*)(out + (long)v * D))[lane] = make_float2(accx * inv, accy * inv);
    }
}

extern "C" void kernel_launch(void* const* d_in, const int* in_sizes, int n_in,
                              void* d_out, int out_size, void* d_ws, size_t ws_size,
                              hipStream_t stream) {
    const float* hidden = (const float*)d_in[0];
    const float* W      = (const float*)d_in[1];
    const int*   seg    = (const int*)d_in[2];
    const int*   nbr    = (const int*)d_in[3];
    float*       out    = (float*)d_out;

    const int Ddim = in_sizes[1];           // 100
    const int n    = in_sizes[0] / Ddim;    // 50000
    const int P    = in_sizes[2];           // ~1.3M pairs

    int* row_ptr = (int*)d_ws;              // (n+1) ints

    hipLaunchKernelGGL(build_row_ptr, dim3((P + 255) / 256), dim3(256), 0, stream,
                       seg, row_ptr, n, P);
    hipLaunchKernelGGL(gat_agg_kernel, dim3((n + 3) / 4), dim3(256), 0, stream,
                       hidden, W, nbr, row_ptr, out, n);
}